// Round 1
// 234.646 us; speedup vs baseline: 1.1180x; 1.1180x over previous
//
#include <hip/hip_runtime.h>

#define NEG_SLOPE 0.2f
#define RSHIFT 6       // range width 64 dst nodes -> LDS-resident counting sort
#define RW     64
#define MAXNR  800     // supports N <= 51200
#define CHUNKP 8192    // edges per partition block

__device__ __forceinline__ ushort f2bf(float f) {
    union { float f; unsigned u; } c; c.f = f;
    unsigned u = c.u;
    return (ushort)((u + 0x7fffu + ((u >> 16) & 1u)) >> 16);   // RNE
}
__device__ __forceinline__ float bflo(unsigned u) { return __uint_as_float(u << 16); }
__device__ __forceinline__ float bfhi(unsigned u) { return __uint_as_float(u & 0xffff0000u); }

// ---------------- mega: partition FIRST (overlaps under A/B), then copy/convert,
// then scores. out[:, :128]=x + xbf=bf16(x) | scores | edge partition
__global__ __launch_bounds__(256) void mega_kernel(
    const float* __restrict__ x, const float* __restrict__ wu,
    const float* __restrict__ bu, const float* __restrict__ wv,
    const int* __restrict__ s0, const int* __restrict__ d0,
    const int* __restrict__ s1, const int* __restrict__ d1,
    float* __restrict__ out, ushort* __restrict__ xbf,
    float* __restrict__ su, float* __restrict__ sv,
    int* __restrict__ gcur, unsigned* __restrict__ pairs,
    int N, int E, int nr, int cap, int convBlocks, int scoreBlocks, int ppset)
{
    __shared__ float wlds[32 * 129];          // 16.5 KB, also aliased by partition
    int* smi = (int*)wlds;
    int tid = threadIdx.x;
    int bid = blockIdx.x;

    if (bid < 2 * ppset) {                    // ---- role C: partition edges
        // into per-(set,range) (dst<<16|src) segments. Scheduled FIRST so its
        // dependent atomic/scatter chain hides under roles A/B.
        int pb = bid;
        int t = pb / ppset, c = pb % ppset;
        const int* ss = t ? s1 : s0;
        const int* dd = t ? d1 : d0;
        int beg = c * CHUNKP, end = min(E, beg + CHUNKP);
        int* lcnt = smi; int* gb = smi + MAXNR; int* lrun = smi + 2 * MAXNR;
        for (int i = tid; i < nr; i += 256) lcnt[i] = 0;
        __syncthreads();
        for (int e = beg + tid; e < end; e += 256)
            atomicAdd(&lcnt[dd[e] >> RSHIFT], 1);
        __syncthreads();
        for (int i = tid; i < nr; i += 256) {
            gb[i] = atomicAdd(&gcur[t * nr + i], lcnt[i]);
            lrun[i] = 0;
        }
        __syncthreads();
        unsigned* pt = pairs + (size_t)t * nr * cap;
        for (int e = beg + tid; e < end; e += 256) {
            int dst = dd[e], src = ss[e];
            int rr = dst >> RSHIFT;
            int pos = atomicAdd(&lrun[rr], 1);
            pt[(size_t)rr * cap + gb[rr] + pos] = ((unsigned)dst << 16) | (unsigned)src;
        }
        return;
    }
    if (bid < 2 * ppset + convBlocks) {       // ---- role A: copy + bf16 convert
        int i = (bid - 2 * ppset) * 256 + tid;
        if (i < N * 32) {
            float4 v = ((const float4*)x)[i];
            int n = i >> 5, q = i & 31;
            ((float4*)out)[(size_t)n * 96 + q] = v;
            ushort4 b;
            b.x = f2bf(v.x); b.y = f2bf(v.y); b.z = f2bf(v.z); b.w = f2bf(v.w);
            *(ushort4*)(xbf + (size_t)i * 4) = b;
        }
        return;
    }
    // ---- role B: scores (R5-proven)
    for (int i = tid; i < 4096; i += 256) {
        int o = i >> 7, k = i & 127;
        wlds[o * 129 + k] = (o < 16) ? wu[i] : wv[i - 2048];
    }
    __syncthreads();
    int o = tid & 15;
    int n = (bid - 2 * ppset - convBlocks) * 16 + (tid >> 4);
    if (n >= N) return;
    const float4* xr4 = (const float4*)(x + (size_t)n * 128);
    const float* wur = wlds + o * 129;
    const float* wvr = wlds + (16 + o) * 129;
    float au = 0.f, av = 0.f;
#pragma unroll
    for (int kk = 0; kk < 32; ++kk) {
        float4 xv = xr4[kk];
        int k = kk * 4;
        au = fmaf(xv.x, wur[k],     au);  av = fmaf(xv.x, wvr[k],     av);
        au = fmaf(xv.y, wur[k + 1], au);  av = fmaf(xv.y, wvr[k + 1], av);
        au = fmaf(xv.z, wur[k + 2], au);  av = fmaf(xv.z, wvr[k + 2], av);
        au = fmaf(xv.w, wur[k + 3], au);  av = fmaf(xv.w, wvr[k + 3], av);
    }
    su[n * 16 + o] = au + bu[o];
    sv[n * 16 + o] = av;
}

// ---------------- buildagg: per-(range,set) block. LDS counting-sort of the
// range's ~1024 edges, then per-node single-pass softmax + gather-aggregate.
// Acc phase: 4 edges in flight x 16 lanes x uint4 (16B) gathers, unrolled x2
// => 2 independent 16B gathers per wave-iteration (4x MLP vs uint2/2-edge).
__global__ __launch_bounds__(256, 8) void buildagg_kernel(
    const ushort* __restrict__ xbf, const float* __restrict__ su,
    const float* __restrict__ sv, const int* __restrict__ gcur,
    const unsigned* __restrict__ pairs, float* __restrict__ out,
    int N, int E, int nr, int cap)
{
    __shared__ ushort srcs[1408];             // sorted src ids (cap <= 1344)
    __shared__ int offl[65];
    __shared__ int cursor[64];
    __shared__ __align__(16) float ev4[4][512];
    int r = blockIdx.x, t = blockIdx.y, tid = threadIdx.x;
    int m = gcur[t * nr + r];
    if (m > cap) m = cap;                     // safety (never expected)
    const unsigned* p = pairs + ((size_t)t * nr + r) * cap;

    if (tid < 64) cursor[tid] = 0;
    __syncthreads();
    for (int i = tid; i < m; i += 256)        // pass 1: histogram (local node id)
        atomicAdd(&cursor[(p[i] >> 16) & (RW - 1)], 1);
    __syncthreads();
    if (tid < 64) {                           // 64-wide shfl scan -> offsets
        int v = cursor[tid];
        int incl = v;
#pragma unroll
        for (int d = 1; d < 64; d <<= 1) {
            int o = __shfl(incl, tid - d);
            if (tid >= d) incl += o;
        }
        offl[tid + 1] = incl;
        if (tid == 0) offl[0] = 0;
        cursor[tid] = incl - v;               // exclusive -> scatter cursor
    }
    __syncthreads();
    for (int i = tid; i < m; i += 256) {      // pass 2: scatter into LDS bucket
        unsigned v = p[i];
        int pos = atomicAdd(&cursor[(v >> 16) & (RW - 1)], 1);
        srcs[pos] = (ushort)(v & 0xffffu);
    }
    __syncthreads();

    // ---- agg: wave w handles local nodes w, w+4, ...
    int wid = tid >> 6, lane = tid & 63;
    int h = lane & 7, e8 = lane >> 3;
    int g2 = lane >> 4, q16 = lane & 15;
    int j0 = q16 * 8;                         // 8 dims/lane, heads 0..7 in order
    float* ev = ev4[wid];
    for (int ln = wid; ln < RW; ln += 4) {
        int n = (r << RSHIFT) + ln;
        if (n >= N) break;
        int beg = offl[ln], end = offl[ln + 1];
        float vh = sv[n * 16 + t * 8 + h];
        float a0 = 0.f, a1 = 0.f, a2 = 0.f, a3 = 0.f;
        float a4 = 0.f, a5 = 0.f, a6 = 0.f, a7 = 0.f;
        float l = 0.f;
        for (int cbeg = beg; cbeg < end; cbeg += 64) {
            int cnt = min(end - cbeg, 64);
            int gmax = (cnt + 7) >> 3;
            for (int g = 0; g < gmax; g += 2) {   // e-phase: 2x(8 edges x 8 heads)
                int ea = g * 8 + e8, eb = ea + 8;
                int sa = srcs[cbeg + ((ea < cnt) ? ea : 0)];
                int sb = srcs[cbeg + ((eb < cnt) ? eb : 0)];
                float fa = su[sa * 16 + t * 8 + h];
                float fb = su[sb * 16 + t * 8 + h];
                float sca = fa + vh;
                float scb = fb + vh;
                sca = (sca >= 0.f) ? sca : NEG_SLOPE * sca;
                scb = (scb >= 0.f) ? scb : NEG_SLOPE * scb;
                float eea = (ea < cnt) ? __expf(sca) : 0.f;
                float eeb = (eb < cnt) ? __expf(scb) : 0.f;
                l += eea;
                l += eeb;
                ev[ea * 8 + h] = eea;             // ea*8+h <= 511
                ev[eb * 8 + h] = eeb;             // zero-fill guarantees acc reads 0
            }
            int quads = (cnt + 3) >> 2;
            for (int i4 = 0; i4 < quads; i4 += 2) {   // acc: 8 edges/iter/wave
                int e0 = (i4 << 2) + g2, e1 = e0 + 4; // e1 <= 63 for all cnt<=64
                int sA = srcs[cbeg + ((e0 < cnt) ? e0 : 0)];
                int sB = srcs[cbeg + ((e1 < cnt) ? e1 : 0)];
                uint4 uA = *(const uint4*)(xbf + (size_t)sA * 128 + j0);
                uint4 uB = *(const uint4*)(xbf + (size_t)sB * 128 + j0);
                float4 pA0 = *(const float4*)(ev + e0 * 8);
                float4 pA1 = *(const float4*)(ev + e0 * 8 + 4);
                float4 pB0 = *(const float4*)(ev + e1 * 8);
                float4 pB1 = *(const float4*)(ev + e1 * 8 + 4);
                a0 = fmaf(bflo(uA.x), pA0.x, a0);
                a1 = fmaf(bfhi(uA.x), pA0.y, a1);
                a2 = fmaf(bflo(uA.y), pA0.z, a2);
                a3 = fmaf(bfhi(uA.y), pA0.w, a3);
                a4 = fmaf(bflo(uA.z), pA1.x, a4);
                a5 = fmaf(bfhi(uA.z), pA1.y, a5);
                a6 = fmaf(bflo(uA.w), pA1.z, a6);
                a7 = fmaf(bfhi(uA.w), pA1.w, a7);
                a0 = fmaf(bflo(uB.x), pB0.x, a0);
                a1 = fmaf(bfhi(uB.x), pB0.y, a1);
                a2 = fmaf(bflo(uB.y), pB0.z, a2);
                a3 = fmaf(bfhi(uB.y), pB0.w, a3);
                a4 = fmaf(bflo(uB.z), pB1.x, a4);
                a5 = fmaf(bfhi(uB.z), pB1.y, a5);
                a6 = fmaf(bflo(uB.w), pB1.z, a6);
                a7 = fmaf(bfhi(uB.w), pB1.w, a7);
            }
        }
        l += __shfl_xor(l, 8);
        l += __shfl_xor(l, 16);
        l += __shfl_xor(l, 32);
        float invl = (l > 0.f) ? (1.f / l) : 0.f;
        a0 += __shfl_xor(a0, 16); a0 += __shfl_xor(a0, 32);
        a1 += __shfl_xor(a1, 16); a1 += __shfl_xor(a1, 32);
        a2 += __shfl_xor(a2, 16); a2 += __shfl_xor(a2, 32);
        a3 += __shfl_xor(a3, 16); a3 += __shfl_xor(a3, 32);
        a4 += __shfl_xor(a4, 16); a4 += __shfl_xor(a4, 32);
        a5 += __shfl_xor(a5, 16); a5 += __shfl_xor(a5, 32);
        a6 += __shfl_xor(a6, 16); a6 += __shfl_xor(a6, 32);
        a7 += __shfl_xor(a7, 16); a7 += __shfl_xor(a7, 32);
        float ih0 = __shfl(invl, 0);
        float ih1 = __shfl(invl, 1);
        float ih2 = __shfl(invl, 2);
        float ih3 = __shfl(invl, 3);
        float ih4 = __shfl(invl, 4);
        float ih5 = __shfl(invl, 5);
        float ih6 = __shfl(invl, 6);
        float ih7 = __shfl(invl, 7);
        if (g2 == 0) {
            float* op = out + (size_t)n * 384 + 128 + (size_t)t * 128 + j0;
            *(float4*)op       = make_float4(a0 * ih0, a1 * ih1, a2 * ih2, a3 * ih3);
            *(float4*)(op + 4) = make_float4(a4 * ih4, a5 * ih5, a6 * ih6, a7 * ih7);
        }
    }
}

extern "C" void kernel_launch(void* const* d_in, const int* in_sizes, int n_in,
                              void* d_out, int out_size, void* d_ws, size_t ws_size,
                              hipStream_t stream)
{
    const float* x  = (const float*)d_in[0];
    const float* wu = (const float*)d_in[1];
    const float* bu = (const float*)d_in[2];
    const float* wv = (const float*)d_in[3];
    const int* s0 = (const int*)d_in[4];
    const int* d0 = (const int*)d_in[5];
    const int* s1 = (const int*)d_in[6];
    const int* d1 = (const int*)d_in[7];
    float* out = (float*)d_out;
    int N = in_sizes[0] / 128;
    int E = in_sizes[4];

    int nr = ((N - 1) >> RSHIFT) + 1;               // 782 for N=50000 (<= MAXNR)
    long long mean = (long long)RW * E / N;         // ~1024
    int cap = (int)(mean + mean / 4 + 64);          // 1344 (>9 sigma margin)

    char* ws = (char*)d_ws;
    size_t o = 0;
    auto alloc = [&](size_t bytes) -> void* {
        void* p = ws + o;
        o = (o + bytes + 255) & ~(size_t)255;
        return p;
    };
    float* su       = (float*)alloc((size_t)N * 16 * 4);
    float* sv       = (float*)alloc((size_t)N * 16 * 4);
    int* gcur       = (int*)alloc((size_t)2 * nr * 4);
    unsigned* pairs = (unsigned*)alloc((size_t)2 * nr * cap * 4);
    ushort* xbf     = (ushort*)alloc((size_t)N * 128 * 2);

    int convBlocks  = (N * 32 + 255) / 256;         // 6250
    int scoreBlocks = (N + 15) / 16;                // 3125
    int ppset       = (E + CHUNKP - 1) / CHUNKP;    // 98

    hipMemsetAsync(gcur, 0, (size_t)2 * nr * 4, stream);
    mega_kernel<<<convBlocks + scoreBlocks + 2 * ppset, 256, 0, stream>>>(
        x, wu, bu, wv, s0, d0, s1, d1, out, xbf, su, sv,
        gcur, pairs, N, E, nr, cap, convBlocks, scoreBlocks, ppset);
    buildagg_kernel<<<dim3(nr, 2), 256, 0, stream>>>(
        xbf, su, sv, gcur, pairs, out, N, E, nr, cap);
}

// Round 2
// 231.592 us; speedup vs baseline: 1.1327x; 1.0132x over previous
//
#include <hip/hip_runtime.h>

#define NEG_SLOPE 0.2f
#define RSHIFT 5       // range width 32 dst nodes -> LDS-resident counting sort
#define RW     32
#define MAXNR  1600    // supports N <= 51200
#define CHUNKP 8192    // edges per partition block

__device__ __forceinline__ ushort f2bf(float f) {
    union { float f; unsigned u; } c; c.f = f;
    unsigned u = c.u;
    return (ushort)((u + 0x7fffu + ((u >> 16) & 1u)) >> 16);   // RNE
}
__device__ __forceinline__ float bflo(unsigned u) { return __uint_as_float(u << 16); }
__device__ __forceinline__ float bfhi(unsigned u) { return __uint_as_float(u & 0xffff0000u); }

// ---------------- mega: partition FIRST (overlaps under scores), then fused
// scores+copy+convert: each score block stages its 16 x-rows in LDS, emits
// out[:, :128] and xbf during staging, computes scores from LDS (x read ONCE).
__global__ __launch_bounds__(256) void mega_kernel(
    const float* __restrict__ x, const float* __restrict__ wu,
    const float* __restrict__ bu, const float* __restrict__ wv,
    const int* __restrict__ s0, const int* __restrict__ d0,
    const int* __restrict__ s1, const int* __restrict__ d1,
    float* __restrict__ out, ushort* __restrict__ xbf,
    float* __restrict__ su, float* __restrict__ sv,
    int* __restrict__ gcur, unsigned* __restrict__ pairs,
    int N, int E, int nr, int cap, int scoreBlocks, int ppset)
{
    __shared__ __align__(16) float smemf[32 * 129 + 16 * 132];  // 24.96 KB
    int* smi = (int*)smemf;                   // role C alias (needs 3*MAXNR=4800)
    float* wlds = smemf;                      // weights 32x129
    float* xtile = smemf + 32 * 129;          // x rows  16x132 (pad -> 2-way)
    int tid = threadIdx.x;
    int bid = blockIdx.x;

    if (bid < 2 * ppset) {                    // ---- role C: partition edges
        // into per-(set,range) (dst<<16|src) segments. Scheduled FIRST so its
        // dependent atomic/scatter chain hides under the score blocks.
        int pb = bid;
        int t = pb / ppset, c = pb % ppset;
        const int* ss = t ? s1 : s0;
        const int* dd = t ? d1 : d0;
        int beg = c * CHUNKP, end = min(E, beg + CHUNKP);
        int* lcnt = smi; int* gb = smi + MAXNR; int* lrun = smi + 2 * MAXNR;
        for (int i = tid; i < nr; i += 256) lcnt[i] = 0;
        __syncthreads();
        for (int e = beg + tid; e < end; e += 256)
            atomicAdd(&lcnt[dd[e] >> RSHIFT], 1);
        __syncthreads();
        for (int i = tid; i < nr; i += 256) {
            gb[i] = atomicAdd(&gcur[t * nr + i], lcnt[i]);
            lrun[i] = 0;
        }
        __syncthreads();
        unsigned* pt = pairs + (size_t)t * nr * cap;
        for (int e = beg + tid; e < end; e += 256) {
            int dst = dd[e], src = ss[e];
            int rr = dst >> RSHIFT;
            int pos = atomicAdd(&lrun[rr], 1);
            pt[(size_t)rr * cap + gb[rr] + pos] = ((unsigned)dst << 16) | (unsigned)src;
        }
        return;
    }
    // ---- role B (fused): stage 16 rows + emit out/xbf, then scores from LDS
    int nb = bid - 2 * ppset;                 // 0..scoreBlocks-1
    int base = nb * 16;
    for (int i = tid; i < 4096; i += 256) {
        int o = i >> 7, k = i & 127;
        wlds[o * 129 + k] = (o < 16) ? wu[i] : wv[i - 2048];
    }
    for (int i2 = tid; i2 < 512; i2 += 256) { // 16 rows x 32 float4
        int I = nb * 512 + i2;                // global float4 index into x
        int nl = i2 >> 5, q = i2 & 31;
        int n = base + nl;
        float4 v = make_float4(0.f, 0.f, 0.f, 0.f);
        if (n < N) {
            v = ((const float4*)x)[I];
            ((float4*)out)[(size_t)n * 96 + q] = v;
            ushort4 b;
            b.x = f2bf(v.x); b.y = f2bf(v.y); b.z = f2bf(v.z); b.w = f2bf(v.w);
            *(ushort4*)(xbf + (size_t)I * 4) = b;
        }
        ((float4*)(xtile + nl * 132))[q] = v;
    }
    __syncthreads();
    int o = tid & 15;
    int nl = tid >> 4;
    int n = base + nl;
    if (n >= N) return;
    const float4* xr4 = (const float4*)(xtile + nl * 132);
    const float* wur = wlds + o * 129;
    const float* wvr = wlds + (16 + o) * 129;
    float au = 0.f, av = 0.f;
#pragma unroll
    for (int kk = 0; kk < 32; ++kk) {
        float4 xv = xr4[kk];
        int k = kk * 4;
        au = fmaf(xv.x, wur[k],     au);  av = fmaf(xv.x, wvr[k],     av);
        au = fmaf(xv.y, wur[k + 1], au);  av = fmaf(xv.y, wvr[k + 1], av);
        au = fmaf(xv.z, wur[k + 2], au);  av = fmaf(xv.z, wvr[k + 2], av);
        au = fmaf(xv.w, wur[k + 3], au);  av = fmaf(xv.w, wvr[k + 3], av);
    }
    su[n * 16 + o] = au + bu[o];
    sv[n * 16 + o] = av;
}

// ---------------- buildagg: per-(range,set) block. LDS counting-sort of the
// range's ~512 edges, then per-node single-pass softmax + gather-aggregate.
// RSHIFT=5 doubles the grid (12.2 blocks/CU) so the CU's 8-block residency cap
// is saturated -> ~2x waves/SIMD for gather-latency hiding.
__global__ __launch_bounds__(256, 8) void buildagg_kernel(
    const ushort* __restrict__ xbf, const float* __restrict__ su,
    const float* __restrict__ sv, const int* __restrict__ gcur,
    const unsigned* __restrict__ pairs, float* __restrict__ out,
    int N, int E, int nr, int cap)
{
    __shared__ ushort srcs[768];              // sorted src ids (cap <= 704)
    __shared__ int offl[33];
    __shared__ int cursor[32];
    __shared__ __align__(16) float ev4[4][512];
    int r = blockIdx.x, t = blockIdx.y, tid = threadIdx.x;
    int m = gcur[t * nr + r];
    if (m > cap) m = cap;                     // safety (never expected)
    const unsigned* p = pairs + ((size_t)t * nr + r) * cap;

    if (tid < 32) cursor[tid] = 0;
    __syncthreads();
    for (int i = tid; i < m; i += 256)        // pass 1: histogram (local node id)
        atomicAdd(&cursor[(p[i] >> 16) & (RW - 1)], 1);
    __syncthreads();
    if (tid < 32) {                           // 32-wide shfl scan -> offsets
        int v = cursor[tid];
        int incl = v;
#pragma unroll
        for (int d = 1; d < 32; d <<= 1) {
            int o = __shfl(incl, tid - d);
            if (tid >= d) incl += o;
        }
        offl[tid + 1] = incl;
        if (tid == 0) offl[0] = 0;
        cursor[tid] = incl - v;               // exclusive -> scatter cursor
    }
    __syncthreads();
    for (int i = tid; i < m; i += 256) {      // pass 2: scatter into LDS bucket
        unsigned v = p[i];
        int pos = atomicAdd(&cursor[(v >> 16) & (RW - 1)], 1);
        srcs[pos] = (ushort)(v & 0xffffu);
    }
    __syncthreads();

    // ---- agg: wave w handles local nodes w, w+4, ...
    int wid = tid >> 6, lane = tid & 63;
    int h = lane & 7, e8 = lane >> 3;
    int g2 = lane >> 4, q16 = lane & 15;
    int j0 = q16 * 8;                         // 8 dims/lane, heads 0..7 in order
    float* ev = ev4[wid];
    for (int ln = wid; ln < RW; ln += 4) {
        int n = (r << RSHIFT) + ln;
        if (n >= N) break;
        int beg = offl[ln], end = offl[ln + 1];
        float vh = sv[n * 16 + t * 8 + h];
        float a0 = 0.f, a1 = 0.f, a2 = 0.f, a3 = 0.f;
        float a4 = 0.f, a5 = 0.f, a6 = 0.f, a7 = 0.f;
        float l = 0.f;
        for (int cbeg = beg; cbeg < end; cbeg += 64) {
            int cnt = min(end - cbeg, 64);
            int gmax = (cnt + 7) >> 3;
            for (int g = 0; g < gmax; g += 2) {   // e-phase: 2x(8 edges x 8 heads)
                int ea = g * 8 + e8, eb = ea + 8;
                int sa = srcs[cbeg + ((ea < cnt) ? ea : 0)];
                int sb = srcs[cbeg + ((eb < cnt) ? eb : 0)];
                float fa = su[sa * 16 + t * 8 + h];
                float fb = su[sb * 16 + t * 8 + h];
                float sca = fa + vh;
                float scb = fb + vh;
                sca = (sca >= 0.f) ? sca : NEG_SLOPE * sca;
                scb = (scb >= 0.f) ? scb : NEG_SLOPE * scb;
                float eea = (ea < cnt) ? __expf(sca) : 0.f;
                float eeb = (eb < cnt) ? __expf(scb) : 0.f;
                l += eea;
                l += eeb;
                ev[ea * 8 + h] = eea;             // ea*8+h <= 511
                ev[eb * 8 + h] = eeb;             // zero-fill guarantees acc reads 0
            }
            int quads = (cnt + 3) >> 2;
            for (int i4 = 0; i4 < quads; i4 += 2) {   // acc: 8 edges/iter/wave
                int e0 = (i4 << 2) + g2, e1 = e0 + 4; // e1 <= 63 for all cnt<=64
                int sA = srcs[cbeg + ((e0 < cnt) ? e0 : 0)];
                int sB = srcs[cbeg + ((e1 < cnt) ? e1 : 0)];
                uint4 uA = *(const uint4*)(xbf + (size_t)sA * 128 + j0);
                uint4 uB = *(const uint4*)(xbf + (size_t)sB * 128 + j0);
                float4 pA0 = *(const float4*)(ev + e0 * 8);
                float4 pA1 = *(const float4*)(ev + e0 * 8 + 4);
                float4 pB0 = *(const float4*)(ev + e1 * 8);
                float4 pB1 = *(const float4*)(ev + e1 * 8 + 4);
                a0 = fmaf(bflo(uA.x), pA0.x, a0);
                a1 = fmaf(bfhi(uA.x), pA0.y, a1);
                a2 = fmaf(bflo(uA.y), pA0.z, a2);
                a3 = fmaf(bfhi(uA.y), pA0.w, a3);
                a4 = fmaf(bflo(uA.z), pA1.x, a4);
                a5 = fmaf(bfhi(uA.z), pA1.y, a5);
                a6 = fmaf(bflo(uA.w), pA1.z, a6);
                a7 = fmaf(bfhi(uA.w), pA1.w, a7);
                a0 = fmaf(bflo(uB.x), pB0.x, a0);
                a1 = fmaf(bfhi(uB.x), pB0.y, a1);
                a2 = fmaf(bflo(uB.y), pB0.z, a2);
                a3 = fmaf(bfhi(uB.y), pB0.w, a3);
                a4 = fmaf(bflo(uB.z), pB1.x, a4);
                a5 = fmaf(bfhi(uB.z), pB1.y, a5);
                a6 = fmaf(bflo(uB.w), pB1.z, a6);
                a7 = fmaf(bfhi(uB.w), pB1.w, a7);
            }
        }
        l += __shfl_xor(l, 8);
        l += __shfl_xor(l, 16);
        l += __shfl_xor(l, 32);
        float invl = (l > 0.f) ? (1.f / l) : 0.f;
        a0 += __shfl_xor(a0, 16); a0 += __shfl_xor(a0, 32);
        a1 += __shfl_xor(a1, 16); a1 += __shfl_xor(a1, 32);
        a2 += __shfl_xor(a2, 16); a2 += __shfl_xor(a2, 32);
        a3 += __shfl_xor(a3, 16); a3 += __shfl_xor(a3, 32);
        a4 += __shfl_xor(a4, 16); a4 += __shfl_xor(a4, 32);
        a5 += __shfl_xor(a5, 16); a5 += __shfl_xor(a5, 32);
        a6 += __shfl_xor(a6, 16); a6 += __shfl_xor(a6, 32);
        a7 += __shfl_xor(a7, 16); a7 += __shfl_xor(a7, 32);
        float ih0 = __shfl(invl, 0);
        float ih1 = __shfl(invl, 1);
        float ih2 = __shfl(invl, 2);
        float ih3 = __shfl(invl, 3);
        float ih4 = __shfl(invl, 4);
        float ih5 = __shfl(invl, 5);
        float ih6 = __shfl(invl, 6);
        float ih7 = __shfl(invl, 7);
        if (g2 == 0) {
            float* op = out + (size_t)n * 384 + 128 + (size_t)t * 128 + j0;
            *(float4*)op       = make_float4(a0 * ih0, a1 * ih1, a2 * ih2, a3 * ih3);
            *(float4*)(op + 4) = make_float4(a4 * ih4, a5 * ih5, a6 * ih6, a7 * ih7);
        }
    }
}

extern "C" void kernel_launch(void* const* d_in, const int* in_sizes, int n_in,
                              void* d_out, int out_size, void* d_ws, size_t ws_size,
                              hipStream_t stream)
{
    const float* x  = (const float*)d_in[0];
    const float* wu = (const float*)d_in[1];
    const float* bu = (const float*)d_in[2];
    const float* wv = (const float*)d_in[3];
    const int* s0 = (const int*)d_in[4];
    const int* d0 = (const int*)d_in[5];
    const int* s1 = (const int*)d_in[6];
    const int* d1 = (const int*)d_in[7];
    float* out = (float*)d_out;
    int N = in_sizes[0] / 128;
    int E = in_sizes[4];

    int nr = ((N - 1) >> RSHIFT) + 1;               // 1563 for N=50000 (<= MAXNR)
    long long mean = (long long)RW * E / N;         // ~512
    int cap = (int)(mean + mean / 4 + 64);          // 704 (>8 sigma margin)

    char* ws = (char*)d_ws;
    size_t o = 0;
    auto alloc = [&](size_t bytes) -> void* {
        void* p = ws + o;
        o = (o + bytes + 255) & ~(size_t)255;
        return p;
    };
    float* su       = (float*)alloc((size_t)N * 16 * 4);
    float* sv       = (float*)alloc((size_t)N * 16 * 4);
    int* gcur       = (int*)alloc((size_t)2 * nr * 4);
    unsigned* pairs = (unsigned*)alloc((size_t)2 * nr * cap * 4);
    ushort* xbf     = (ushort*)alloc((size_t)N * 128 * 2);

    int scoreBlocks = (N + 15) / 16;                // 3125
    int ppset       = (E + CHUNKP - 1) / CHUNKP;    // 98

    hipMemsetAsync(gcur, 0, (size_t)2 * nr * 4, stream);
    mega_kernel<<<scoreBlocks + 2 * ppset, 256, 0, stream>>>(
        x, wu, bu, wv, s0, d0, s1, d1, out, xbf, su, sv,
        gcur, pairs, N, E, nr, cap, scoreBlocks, ppset);
    buildagg_kernel<<<dim3(nr, 2), 256, 0, stream>>>(
        xbf, su, sv, gcur, pairs, out, N, E, nr, cap);
}